// Round 7
// baseline (131.176 us; speedup 1.0000x reference)
//
#include <hip/hip_runtime.h>

typedef __attribute__((ext_vector_type(8))) short short8;
typedef __attribute__((ext_vector_type(4))) float floatx4;
typedef __attribute__((ext_vector_type(4))) unsigned int uint32x4;

#define CIN  256
#define NSP  2048   // T*H*W
#define COUT 256
#define FF   512
#define NSHARD 32
#define PITCH 128   // u32 per n-row of the transposed bf16 panel

// Module-scope scratch (d_ws unused; harness's 256 MiB ws poison-fills are
// unconditional -- round 2/6 -- so workspace vs globals is perf-neutral).
__device__ unsigned short g_M[COUT * CIN];        // 128 KiB bf16 M = Wout @ Wv
__device__ float g_shard[NSHARD][2][COUT];        // 64 KiB BN partials
__device__ unsigned int g_done;                   // k2 arrival counter

__device__ __forceinline__ unsigned short f2bf_rne(float f) {
  unsigned int u = __float_as_uint(f);
  u += 0x7fffu + ((u >> 16) & 1u);
  return (unsigned short)(u >> 16);
}

// pack two f32 -> bf16x2 (round-half-up: +0x8000 then take hi16) in 3 VALU
__device__ __forceinline__ unsigned int pack_bf16_hu(float lo, float hi) {
  unsigned int a = __float_as_uint(lo) + 0x8000u;
  unsigned int b = __float_as_uint(hi) + 0x8000u;
  return __builtin_amdgcn_perm(b, a, 0x07060302u);
}

// ---------------------------------------------------------------------------
// K1: M = Wout @ Wv (bf16). 64 blocks x 4 rows x 1024 threads.
// Block 0 zeroes the BN shards and the k2 arrival counter.
// ---------------------------------------------------------------------------
__global__ __launch_bounds__(1024) void k1_m(
    const float* __restrict__ Wv, const float* __restrict__ Wout)
{
  __shared__ float ws[4 * FF];        // 4 Wout rows, 8 KiB
  __shared__ float red[4][4][256];    // [f-chunk][row][c], 16 KiB
  const int tid = threadIdx.x;
  const int r0  = blockIdx.x * 4;
  if (blockIdx.x == 0) {
    float* gs = &g_shard[0][0][0];    // 16384 floats
    #pragma unroll
    for (int i = 0; i < 16; ++i) gs[tid + i * 1024] = 0.f;
    if (tid == 0) g_done = 0u;        // reset arrival counter (pre-k2, in-stream)
  }
  ws[tid]        = Wout[(size_t)r0 * FF + tid];
  ws[tid + 1024] = Wout[(size_t)r0 * FF + 1024 + tid];
  __syncthreads();
  const int c  = tid & 255;
  const int fs = tid >> 8;            // f-chunk, constant per wave -> ws bcast
  float a0 = 0.f, a1 = 0.f, a2 = 0.f, a3 = 0.f;
  #pragma unroll 8
  for (int f0 = 0; f0 < 128; ++f0) {
    const int f = fs * 128 + f0;
    const float wv = Wv[(size_t)f * 256 + c];   // coalesced, L2-hot
    a0 += ws[f] * wv;
    a1 += ws[FF + f] * wv;
    a2 += ws[2 * FF + f] * wv;
    a3 += ws[3 * FF + f] * wv;
  }
  red[fs][0][c] = a0; red[fs][1][c] = a1;
  red[fs][2][c] = a2; red[fs][3][c] = a3;
  __syncthreads();
  const int rr = tid >> 8, cc = tid & 255;      // all 1024 threads: 4r x 256c
  float s = red[0][rr][cc] + red[1][rr][cc] + red[2][rr][cc] + red[3][rr][cc];
  g_M[(size_t)(r0 + rr) * 256 + cc] = f2bf_rne(s);
}

// ---------------------------------------------------------------------------
// K2: o = M @ x via bf16 MFMA (transposed swizzled bf16 LDS panel, round 6),
// fused bias+relu+residual AND batchnorm:
//   y stays in acc registers; blocks publish BN shard partials, arrive at
//   g_done, spin to gridDim (flag sync -- 256 blocks <= 512 guaranteed-
//   resident slots at launch_bounds(512,4), so no cooperative launch needed),
//   fold shards into per-oc scale/shift, and write the NORMALIZED y once.
// Removes k3 entirely: its launch + 33.6 MB L2 round-trip + one 16.8 MB
// write. Numerically identical (same y, same y*sc+sh order as k3).
// 256 blocks x 512 thr; XCD pin b = id&7 (256%8==0, bijective).
// ---------------------------------------------------------------------------
__global__ __launch_bounds__(512, 4) void k2_gemm(
    const float* __restrict__ x, const float* __restrict__ bout,
    const float* __restrict__ gamma, const float* __restrict__ beta,
    float* __restrict__ out)
{
  __shared__ __align__(16) unsigned int lxt[64 * PITCH];  // 32 KiB bf16 panel^T
  __shared__ float ls[COUT], lq[COUT];   // partials, then {scale, shift}
  const int tid  = threadIdx.x;
  const int lane = tid & 63;
  const int wave = tid >> 6;
  const int m16  = lane & 15;
  const int q    = lane >> 4;
  const int id   = blockIdx.x;
  const int b    = id & 7;            // XCD pin: batch b -> XCD b
  const int n0   = (id >> 3) * 64;    // 32 n-panels per batch
  const int wocb = (wave & 3) * 64;   // wave's 64 oc rows (4 oc-waves)
  const int wn   = (wave >> 2) * 32;  // wave's 32 n cols  (2 n-waves)

  if (tid < COUT) { ls[tid] = 0.f; lq[tid] = 0.f; }

  // ---- stage x[b][0:256][n0:n0+64] -> bf16, transposed, swizzled ----
  {
    const int cgrp = tid >> 4;        // 0..31: 8-row c group
    const int n4   = tid & 15;        // 16 n4-groups of 4 n
    const int c0   = cgrp * 8;
    const float* gp = x + (size_t)b * CIN * NSP + (size_t)c0 * NSP + n0 + n4 * 4;
    float4 v[8];
    #pragma unroll
    for (int i = 0; i < 8; ++i)       // rows c0..c0+7: 256B-contig per 16 lanes
      v[i] = *(const float4*)(gp + (size_t)i * NSP);
    const float* vf = (const float*)v;  // v[i] component j = vf[i*4+j]
    #pragma unroll
    for (int j = 0; j < 4; ++j) {
      uint32x4 w;
      #pragma unroll
      for (int p = 0; p < 4; ++p)     // c-pair (c0+2p, c0+2p+1), col n4*4+j
        w[p] = pack_bf16_hu(vf[(2 * p) * 4 + j], vf[(2 * p + 1) * 4 + j]);
      const int n = n4 * 4 + j;
      const int idx = (n * PITCH + cgrp * 4) ^ ((n & 7) << 2);
      *(uint32x4*)&lxt[idx] = w;      // ds_write_b128, conflict-free
    }
  }
  __syncthreads();

  floatx4 acc[4][2];
  #pragma unroll
  for (int i = 0; i < 4; ++i)
    #pragma unroll
    for (int j = 0; j < 2; ++j)
      acc[i][j] = (floatx4){0.f, 0.f, 0.f, 0.f};

  const unsigned short* Ab = g_M + (size_t)(wocb + m16) * 256 + q * 8;

  #pragma unroll
  for (int kk = 0; kk < 8; ++kk) {
    short8 av[4];
    #pragma unroll
    for (int ti = 0; ti < 4; ++ti)    // 16B L2-hot loads of M
      av[ti] = *(const short8*)(Ab + (size_t)ti * 16 * 256 + kk * 32);
    short8 bv[2];
    #pragma unroll
    for (int tj = 0; tj < 2; ++tj) {  // one ds_read_b128 per fragment
      const int n = wn + tj * 16 + m16;
      const int idx = (n * PITCH + kk * 16 + q * 4) ^ ((n & 7) << 2);
      bv[tj] = *(const short8*)&lxt[idx];
    }
    #pragma unroll
    for (int ti = 0; ti < 4; ++ti)
      #pragma unroll
      for (int tj = 0; tj < 2; ++tj)
        acc[ti][tj] = __builtin_amdgcn_mfma_f32_16x16x32_bf16(av[ti], bv[tj], acc[ti][tj], 0, 0, 0);
  }

  // ---- epilogue part 1: y = relu(o + bias) + x, kept in acc; stats ----
  // D layout: col(n)=lane&15, row(oc within 16-tile)=q*4+reg
  #pragma unroll
  for (int ti = 0; ti < 4; ++ti) {
    #pragma unroll
    for (int r = 0; r < 4; ++r) {
      const int oc = wocb + ti * 16 + q * 4 + r;
      const float bo = bout[oc];
      float s = 0.f, s2 = 0.f;
      #pragma unroll
      for (int tj = 0; tj < 2; ++tj) {
        const int nl = wn + tj * 16 + m16;
        const size_t gidx = ((size_t)(b * COUT + oc)) * NSP + n0 + nl;
        float o = fmaxf(acc[ti][tj][r] + bo, 0.f);
        float y = x[gidx] + o;        // residual: f32, XCD-L2-hot
        acc[ti][tj][r] = y;           // keep y resident; write after norm
        s += y;
        s2 += y * y;
      }
      #pragma unroll
      for (int d = 1; d < 16; d <<= 1) {  // stays within 16-lane group
        s  += __shfl_xor(s, d, 64);
        s2 += __shfl_xor(s2, d, 64);
      }
      if (m16 == 0) {
        atomicAdd(&ls[oc], s);
        atomicAdd(&lq[oc], s2);
      }
    }
  }
  __syncthreads();
  if (tid < COUT) {
    const int s = id >> 3;            // 32 shards; 8 atomics/address (8 b's)
    atomicAdd(&g_shard[s][0][tid], ls[tid]);
    atomicAdd(&g_shard[s][1][tid], lq[tid]);
    __threadfence();                  // release shard adds device-wide
  }
  __syncthreads();                    // drains vmcnt: all block's adds done

  // ---- flag sync: all 256 blocks' partials published ----
  if (tid == 0) {
    atomicAdd(&g_done, 1u);
    while (__hip_atomic_load(&g_done, __ATOMIC_ACQUIRE,
                             __HIP_MEMORY_SCOPE_AGENT) < gridDim.x)
      __builtin_amdgcn_s_sleep(8);
  }
  __syncthreads();

  // ---- fold shards -> per-oc scale/shift in LDS ----
  if (tid < COUT) {
    float su = 0.f, sq = 0.f;
    #pragma unroll
    for (int i = 0; i < NSHARD; ++i) {   // coherent (agent-scope) loads
      su += __hip_atomic_load(&g_shard[i][0][tid], __ATOMIC_RELAXED,
                              __HIP_MEMORY_SCOPE_AGENT);
      sq += __hip_atomic_load(&g_shard[i][1][tid], __ATOMIC_RELAXED,
                              __HIP_MEMORY_SCOPE_AGENT);
    }
    const float inv_n = 1.f / 16384.f;
    const float m  = su * inv_n;
    const float v  = sq * inv_n - m * m;
    const float sc = gamma[tid] * rsqrtf(v + 1e-5f);
    ls[tid] = sc;
    lq[tid] = beta[tid] - m * sc;
  }
  __syncthreads();

  // ---- epilogue part 2: single normalized write ----
  #pragma unroll
  for (int ti = 0; ti < 4; ++ti) {
    #pragma unroll
    for (int r = 0; r < 4; ++r) {
      const int oc = wocb + ti * 16 + q * 4 + r;
      const float sc = ls[oc], sh = lq[oc];
      #pragma unroll
      for (int tj = 0; tj < 2; ++tj) {
        const int nl = wn + tj * 16 + m16;
        const size_t gidx = ((size_t)(b * COUT + oc)) * NSP + n0 + nl;
        out[gidx] = acc[ti][tj][r] * sc + sh;  // 64B sectors per 16-lane group
      }
    }
  }
}

extern "C" void kernel_launch(void* const* d_in, const int* in_sizes, int n_in,
                              void* d_out, int out_size, void* d_ws, size_t ws_size,
                              hipStream_t stream) {
  const float* x     = (const float*)d_in[0];
  // d_in[1]=Wk, d_in[2]=Wq: dead — softmax rows sum to 1, so agg == V,
  // and o = Wout@(Wv@x) = (Wout@Wv)@x = M@x.
  const float* Wv    = (const float*)d_in[3];
  const float* Wout  = (const float*)d_in[4];
  const float* bout  = (const float*)d_in[5];
  const float* gamma = (const float*)d_in[6];
  const float* beta  = (const float*)d_in[7];
  float* out = (float*)d_out;

  hipLaunchKernelGGL(k1_m,    dim3(64),  dim3(1024), 0, stream, Wv, Wout);
  hipLaunchKernelGGL(k2_gemm, dim3(256), dim3(512),  0, stream,
                     x, bout, gamma, beta, out);
}

// Round 8
// 112.612 us; speedup vs baseline: 1.1648x; 1.1648x over previous
//
#include <hip/hip_runtime.h>

typedef __attribute__((ext_vector_type(8))) short short8;
typedef __attribute__((ext_vector_type(4))) float floatx4;

#define CIN  256
#define NSP  2048   // T*H*W
#define COUT 256
#define FF   512
#define NSHARD 32
#define LPAD 66     // LDS row pitch in dwords for the 64-wide x panel:
                    // 66 ≡ 2 (mod 32) spreads q-groups to <=2-way banks (free)

// Module-scope scratch (d_ws unused; the harness's 256 MiB ws poison-fills
// are unconditional -- rounds 2/6 -- so workspace vs globals is perf-neutral).
// Round-7 lesson: device-wide flag-sync/grid.sync costs 30-50 us on MI355X
// (8 non-coherent XCD L2s) -- never fuse across the BN-stats barrier.
__device__ unsigned short g_M[COUT * CIN];        // 128 KiB bf16 M = Wout @ Wv
// Sharded BN partials: 32 shards x {sum, sumsq} x 256 oc -> 8 atomics/address.
__device__ float g_shard[NSHARD][2][COUT];        // 64 KiB

__device__ __forceinline__ unsigned short f2bf_rne(float f) {
  unsigned int u = __float_as_uint(f);
  u += 0x7fffu + ((u >> 16) & 1u);
  return (unsigned short)(u >> 16);
}

// pack two f32 -> bf16x2 (round-half-up: +0x8000 then take hi16) in 3 VALU
__device__ __forceinline__ unsigned int pack_bf16_hu(float lo, float hi) {
  unsigned int a = __float_as_uint(lo) + 0x8000u;
  unsigned int b = __float_as_uint(hi) + 0x8000u;
  return __builtin_amdgcn_perm(b, a, 0x07060302u);
}

// ---------------------------------------------------------------------------
// K1: M = Wout @ Wv (bf16). 256 blocks (1 row each) x 1024 threads.
// Waves split the f(=512) reduction 4 ways; LDS reduce. Block 0 zeroes shards.
// ---------------------------------------------------------------------------
__global__ __launch_bounds__(1024) void k1_m(
    const float* __restrict__ Wv, const float* __restrict__ Wout)
{
  __shared__ float ws[512];
  __shared__ float red[4][256];
  const int tid = threadIdx.x;
  const int r   = blockIdx.x;
  if (r == 0) {
    float* gs = &g_shard[0][0][0];    // 16384 floats
    #pragma unroll
    for (int i = 0; i < 16; ++i) gs[tid + i * 1024] = 0.f;
  }
  if (tid < 512) ws[tid] = Wout[(size_t)r * 512 + tid];
  __syncthreads();
  const int c  = tid & 255;
  const int fs = tid >> 8;            // constant per wave -> ws[f] broadcast
  float acc = 0.f;
  #pragma unroll 16
  for (int f0 = 0; f0 < 128; ++f0) {
    int f = fs * 128 + f0;
    acc += ws[f] * Wv[(size_t)f * 256 + c];   // coalesced, L2-hot
  }
  red[fs][c] = acc;
  __syncthreads();
  if (tid < 256) {
    float s = red[0][tid] + red[1][tid] + red[2][tid] + red[3][tid];
    g_M[(size_t)r * 256 + tid] = f2bf_rne(s);
  }
}

// ---------------------------------------------------------------------------
// K2: o = M @ x via bf16 MFMA, with the block's x panel STAGED IN LDS.
// 256 blocks x 512 threads; block = full 256 oc x 64 n for one batch.
//   - staging: 8 coalesced float4 loads/thread; one barrier.
//   - B-fragments packed from LDS (pitch-66 rows: <=2-way bank aliasing).
//   - residual x[b][oc][n] == staged panel row oc -> LDS read (CIN==COUT).
//   - x HBM fetch 1x (block covers both oc halves).
//   - XCD pin: b = id&7 -> batch's panel + g_M stay XCD-L2-local.
// Epilogue: bias+relu+residual, f32 y -> out, BN partials -> g_shard.
// ---------------------------------------------------------------------------
__global__ __launch_bounds__(512, 2) void k2_gemm(
    const float* __restrict__ x, const float* __restrict__ bout,
    float* __restrict__ out)
{
  __shared__ float lx[CIN * LPAD];    // 256 x 66 dwords = 66 KiB
  __shared__ float ls[COUT], lq[COUT];
  const int tid  = threadIdx.x;
  const int lane = tid & 63;
  const int wave = tid >> 6;
  const int m16  = lane & 15;
  const int q    = lane >> 4;
  const int id   = blockIdx.x;
  const int b    = id & 7;            // XCD pin: batch b -> XCD b (256%8==0)
  const int n0   = (id >> 3) * 64;    // 32 n-panels per batch
  const int wocb = (wave & 3) * 64;   // wave's 64 oc rows
  const int wn   = (wave >> 2) * 32;  // wave's 32 n cols (panel-local)

  if (tid < COUT) { ls[tid] = 0.f; lq[tid] = 0.f; }

  // ---- stage x[b][0:256][n0:n0+64] (64 KiB f32) into LDS ----
  {
    const int n4 = (tid & 15) * 4;
    const int cr = tid >> 5;          // 0..15
    const int ch = (tid >> 4) & 1;    // split 256 rows: cr + 16*(i*2+ch)
    const float* gp = x + (size_t)b * CIN * NSP + n0 + n4;
    #pragma unroll
    for (int i = 0; i < 8; ++i) {
      const int c = cr + 16 * (2 * i + ch);
      const float4 v = *(const float4*)(gp + (size_t)c * NSP);
      float* d = &lx[c * LPAD + n4];
      *(float2*)d       = make_float2(v.x, v.y);   // pitch 66 is 8B-aligned
      *(float2*)(d + 2) = make_float2(v.z, v.w);
    }
  }
  __syncthreads();

  floatx4 acc[4][2];
  #pragma unroll
  for (int i = 0; i < 4; ++i)
    #pragma unroll
    for (int j = 0; j < 2; ++j)
      acc[i][j] = (floatx4){0.f, 0.f, 0.f, 0.f};

  const unsigned short* Ab = g_M + (size_t)(wocb + m16) * 256 + q * 8;

  #pragma unroll
  for (int kk = 0; kk < 8; ++kk) {
    short8 av[4];
    #pragma unroll
    for (int ti = 0; ti < 4; ++ti)
      av[ti] = *(const short8*)(Ab + (size_t)ti * 16 * 256 + kk * 32);
    short8 bv[2];
    #pragma unroll
    for (int tj = 0; tj < 2; ++tj) {
      const int nl = wn + tj * 16 + m16;
      const float* lp = &lx[(kk * 32 + q * 8) * LPAD + nl];
      union { unsigned int u[4]; short8 v; } p;
      #pragma unroll
      for (int j = 0; j < 4; ++j) {
        float f0 = lp[(2 * j) * LPAD];        // c = kk*32+q*8+2j
        float f1 = lp[(2 * j + 1) * LPAD];
        p.u[j] = pack_bf16_hu(f0, f1);
      }
      bv[tj] = p.v;
    }
    #pragma unroll
    for (int ti = 0; ti < 4; ++ti)
      #pragma unroll
      for (int tj = 0; tj < 2; ++tj)
        acc[ti][tj] = __builtin_amdgcn_mfma_f32_16x16x32_bf16(av[ti], bv[tj], acc[ti][tj], 0, 0, 0);
  }

  // D layout: col(n)=lane&15, row(oc within 16-tile)=q*4+reg
  #pragma unroll
  for (int ti = 0; ti < 4; ++ti) {
    #pragma unroll
    for (int r = 0; r < 4; ++r) {
      const int oc = wocb + ti * 16 + q * 4 + r;
      const float bo = bout[oc];
      float s = 0.f, s2 = 0.f;
      #pragma unroll
      for (int tj = 0; tj < 2; ++tj) {
        const int nl = wn + tj * 16 + m16;
        const size_t gidx = ((size_t)(b * COUT + oc)) * NSP + n0 + nl;
        float o = fmaxf(acc[ti][tj][r] + bo, 0.f);
        float y = lx[oc * LPAD + nl] + o;   // residual from staged panel
        out[gidx] = y;                      // f32, 64B sectors per quad
        s += y;
        s2 += y * y;
      }
      #pragma unroll
      for (int d = 1; d < 16; d <<= 1) {    // stays within 16-lane group
        s  += __shfl_xor(s, d, 64);
        s2 += __shfl_xor(s2, d, 64);
      }
      if (m16 == 0) {
        atomicAdd(&ls[oc], s);
        atomicAdd(&lq[oc], s2);
      }
    }
  }
  __syncthreads();
  if (tid < COUT) {
    const int s = id >> 3;            // 32 shards; 8 atomics/address (8 b's)
    atomicAdd(&g_shard[s][0][tid], ls[tid]);
    atomicAdd(&g_shard[s][1][tid], lq[tid]);
  }
}

// ---------------------------------------------------------------------------
// K3: normalize out in place. 2048 blocks = one (b,oc) row of 2048 each.
// Shard sum (32x {sum,sq}) is uniform per block -> scalar-path broadcast
// loads, all L2-hot (64 KiB). scale/shift computed redundantly per thread.
// ---------------------------------------------------------------------------
__global__ __launch_bounds__(256) void k3_norm(
    const float* __restrict__ gamma, const float* __restrict__ beta,
    float* __restrict__ out)
{
  const int row = blockIdx.x;       // b*256 + oc
  const int oc  = row & 255;
  float su = 0.f, sq = 0.f;
  #pragma unroll
  for (int i = 0; i < NSHARD; ++i) {
    su += g_shard[i][0][oc];
    sq += g_shard[i][1][oc];
  }
  const float inv_n = 1.f / 16384.f;
  const float m  = su * inv_n;
  const float v  = sq * inv_n - m * m;
  const float sc = gamma[oc] * rsqrtf(v + 1e-5f);
  const float sh = beta[oc] - m * sc;
  float* p = out + (size_t)row * 2048 + threadIdx.x * 8;
  float4 a = *(const float4*)p;
  float4 c = *(const float4*)(p + 4);
  a.x = a.x * sc + sh; a.y = a.y * sc + sh;
  a.z = a.z * sc + sh; a.w = a.w * sc + sh;
  c.x = c.x * sc + sh; c.y = c.y * sc + sh;
  c.z = c.z * sc + sh; c.w = c.w * sc + sh;
  *(float4*)p = a;
  *(float4*)(p + 4) = c;
}

extern "C" void kernel_launch(void* const* d_in, const int* in_sizes, int n_in,
                              void* d_out, int out_size, void* d_ws, size_t ws_size,
                              hipStream_t stream) {
  const float* x     = (const float*)d_in[0];
  // d_in[1]=Wk, d_in[2]=Wq: dead — softmax rows sum to 1, so agg == V,
  // and o = Wout@(Wv@x) = (Wout@Wv)@x = M@x.
  const float* Wv    = (const float*)d_in[3];
  const float* Wout  = (const float*)d_in[4];
  const float* bout  = (const float*)d_in[5];
  const float* gamma = (const float*)d_in[6];
  const float* beta  = (const float*)d_in[7];
  float* out = (float*)d_out;

  hipLaunchKernelGGL(k1_m,    dim3(256),  dim3(1024), 0, stream, Wv, Wout);
  hipLaunchKernelGGL(k2_gemm, dim3(256),  dim3(512),  0, stream, x, bout, out);
  hipLaunchKernelGGL(k3_norm, dim3(2048), dim3(256),  0, stream,
                     gamma, beta, out);
}